// Round 1
// 289.563 us; speedup vs baseline: 1.1545x; 1.1545x over previous
//
#include <hip/hip_runtime.h>
#include <hip/hip_bf16.h>
#include <stdint.h>

// Problem constants (B,T,D,NH from reference)
#define NHh 16
#define Dm  1024
#define HD  64          // head dim = D/NH
#define Bb  4
#define Tt  4096
#define NCH 128         // chunks along T for the two-pass scans
#define CHL 32          // chunk length (NCH*CHL == Tt)

using bf16 = __hip_bfloat16;
typedef __attribute__((ext_vector_type(8))) short short8;   // 8 bf16 in 4 VGPRs (MFMA A/B frag)
typedef __attribute__((ext_vector_type(4))) float f32x4;    // MFMA C/D frag

__device__ __forceinline__ float bf2f(bf16 v) { return __bfloat162float(v); }

// bf16 bits -> f32 (exact): bf16 is the high 16 bits of f32
__device__ __forceinline__ float b2f(unsigned short u) {
  union { unsigned int i; float f; } x; x.i = ((unsigned int)u) << 16; return x.f;
}

// fast reciprocal via v_rcp_f32 (~1 ulp; inputs are bf16-derived, tolerance is 1e-2)
__device__ __forceinline__ float frcp(float x) {
  float r; asm("v_rcp_f32 %0, %1" : "=v"(r) : "v"(x)); return r;
}

// async global->LDS, 16B per lane. LDS dest is wave-uniform base + lane*16.
__device__ __forceinline__ void gld_lds16(const void* g, void* l) {
  __builtin_amdgcn_global_load_lds(
      (const __attribute__((address_space(1))) unsigned int*)g,
      (__attribute__((address_space(3))) unsigned int*)l, 16, 0, 0);
}

// fp32 -> bf16 cast, vectorized; n divisible by 4
__global__ void cast_f32_to_bf16(const float* __restrict__ in, bf16* __restrict__ out, int n) {
  const int stride = gridDim.x * blockDim.x;
  for (int i = blockIdx.x * blockDim.x + threadIdx.x; i * 4 < n; i += stride) {
    const float4 v = *(const float4*)(in + (size_t)i * 4);
    ushort4 o;
    o.x = __bfloat16_as_ushort(__float2bfloat16(v.x));
    o.y = __bfloat16_as_ushort(__float2bfloat16(v.y));
    o.z = __bfloat16_as_ushort(__float2bfloat16(v.z));
    o.w = __bfloat16_as_ushort(__float2bfloat16(v.w));
    *(ushort4*)(out + (size_t)i * 4) = o;
  }
}

// C[m][n] = sum_k A[m][k] * W[n][k]  (both K-contiguous row-major, bf16)
// 128x128 tile, 256 threads (4 waves in 2x2, each 64x64 = 4x4 MFMA 16x16x32).
// T1 XCD swizzle: grid is (8,128) = 1024 blocks, divisible by 8 XCDs -> bijective
// chunked remap so the 8 N-tiles sharing an A-panel land on ONE XCD's L2.
// WRITE_S1: fuse per-32-row chunk sums of bf16(w)^2 into the epilogue.
template <bool OUT_BF16, bool WRITE_S1>
__global__ __launch_bounds__(256) void gemm_bt(const bf16* __restrict__ A,
                                               const bf16* __restrict__ W,
                                               void* __restrict__ Cout,
                                               float* __restrict__ S1,
                                               int M, int N, int K) {
  __shared__ __align__(16) unsigned short sA[128][32];   // 8 KB
  __shared__ __align__(16) unsigned short sB[128][32];   // 8 KB
  const int tid  = threadIdx.x;
  const int lane = tid & 63;
  const int wave = tid >> 6;
  // XCD-aware swizzle (nwg = 1024 = 8*128, gridDim.x = 8): swz = (bid%8)*128 + bid/8
  const int bid = blockIdx.x + blockIdx.y * gridDim.x;
  const int swz = ((bid & 7) << 7) | (bid >> 3);
  const int bn = (swz & 7) * 128;
  const int bm = (swz >> 3) * 128;
  const int wm = (wave & 1) * 64;
  const int wn = (wave >> 1) * 64;
  const int quad = lane >> 4;
  const int l16  = lane & 15;

  f32x4 acc[4][4] = {};

  // staging map: thread tid covers rows (tid>>2) and (tid>>2)+64, 8 bf16 at col (tid&3)*8
  const int rowL = tid >> 2;          // 0..63
  const int col8 = (tid & 3) * 8;     // 0,8,16,24

  for (int k0 = 0; k0 < K; k0 += 32) {
    const bf16* g0 = A + (size_t)(bm + rowL) * K + (k0 + col8);
    const bf16* g1 = A + (size_t)(bm + 64 + rowL) * K + (k0 + col8);
    gld_lds16(g0, (unsigned short*)sA + wave * 512);
    gld_lds16(g1, (unsigned short*)sA + 2048 + wave * 512);
    const bf16* h0 = W + (size_t)(bn + rowL) * K + (k0 + col8);
    const bf16* h1 = W + (size_t)(bn + 64 + rowL) * K + (k0 + col8);
    gld_lds16(h0, (unsigned short*)sB + wave * 512);
    gld_lds16(h1, (unsigned short*)sB + 2048 + wave * 512);
    __syncthreads();

    short8 af[4], bfv[4];
#pragma unroll
    for (int i = 0; i < 4; i++) af[i]  = *(const short8*)&sA[wm + i * 16 + l16][quad * 8];
#pragma unroll
    for (int j = 0; j < 4; j++) bfv[j] = *(const short8*)&sB[wn + j * 16 + l16][quad * 8];
#pragma unroll
    for (int i = 0; i < 4; i++)
#pragma unroll
      for (int j = 0; j < 4; j++)
        acc[i][j] = __builtin_amdgcn_mfma_f32_16x16x32_bf16(af[i], bfv[j], acc[i][j], 0, 0, 0);
    __syncthreads();
  }

  // C/D layout (HW-verified): col = lane&15, row = (lane>>4)*4 + reg
#pragma unroll
  for (int j = 0; j < 4; j++) {
    const int col = bn + wn + j * 16 + l16;
    float ssum0 = 0.f, ssum1 = 0.f;   // rows 0..31 / 32..63 of this wave's 64-row block
#pragma unroll
    for (int i = 0; i < 4; i++) {
#pragma unroll
      for (int r = 0; r < 4; r++) {
        const int row = bm + wm + i * 16 + quad * 4 + r;
        if constexpr (OUT_BF16) {
          const bf16 hv = __float2bfloat16(acc[i][j][r]);
          ((bf16*)Cout)[(size_t)row * N + col] = hv;
          if constexpr (WRITE_S1) {
            const float fv = bf2f(hv);
            if (i < 2) ssum0 += fv * fv; else ssum1 += fv * fv;
          }
        } else {
          ((float*)Cout)[(size_t)row * N + col] = acc[i][j][r];
        }
      }
    }
    if constexpr (WRITE_S1) {
      // reduce over the 4 quads (same l16 -> same col); each half = one 32-row chunk
      ssum0 += __shfl_xor(ssum0, 16, 64);
      ssum0 += __shfl_xor(ssum0, 32, 64);
      ssum1 += __shfl_xor(ssum1, 16, 64);
      ssum1 += __shfl_xor(ssum1, 32, 64);
      if (quad == 0) {
        const int r0 = bm + wm;           // first row of this wave's 64-row block
        const int b  = r0 >> 12;          // / Tt
        const int c0 = (r0 & (Tt - 1)) >> 5;   // /CHL (=32)
        const int h  = col >> 6, d = col & 63;
        float* s1p = S1 + (((size_t)(b * NHh + h) * NCH) + c0) * HD + d;
        s1p[0]  = ssum0;
        s1p[HD] = ssum1;
      }
    }
  }
}

// penalty[b,t] = (phi[b,t] - cumsum(phi)[b,t]/(t+1))^2 ; 1024-thread block scan per batch
__global__ __launch_bounds__(1024) void phi_penalty_kernel(const float* __restrict__ phi,
                                                           float* __restrict__ penalty) {
  const int b = blockIdx.x;
  const int tid = threadIdx.x;            // 1024
  const int lane = tid & 63, wid = tid >> 6;   // 16 waves
  __shared__ float wsum[16];
  __shared__ float carry_s;
  if (tid == 0) carry_s = 0.f;
  __syncthreads();
  for (int r = 0; r < Tt / 1024; r++) {
    const int t = r * 1024 + tid;
    const float v = phi[b * Tt + t];
    float incl = v;
#pragma unroll
    for (int off = 1; off < 64; off <<= 1) {
      float n = __shfl_up(incl, off, 64);
      if (lane >= off) incl += n;
    }
    if (lane == 63) wsum[wid] = incl;
    __syncthreads();
    float woff = carry_s;
    for (int wpre = 0; wpre < wid; wpre++) woff += wsum[wpre];
    const float csum = woff + incl;
    const float mean = csum / (float)(t + 1);
    const float dphi = v - mean;
    penalty[b * Tt + t] = dphi * dphi;
    __syncthreads();
    if (tid == 0) {
      float s = 0.f;
      for (int w = 0; w < 16; w++) s += wsum[w];
      carry_s += s;
    }
    __syncthreads();
  }
}

// in-place exclusive prefix over chunks, per (b,h,d) — LDS-tile version.
// One block per bh: stage [NCH][HD] tile coalesced, conflict-free column scan, write back.
__global__ __launch_bounds__(64) void prefix_vec(float* __restrict__ S) {
  __shared__ float tile[NCH * HD];          // 32 KB
  const int bh = blockIdx.x, tid = threadIdx.x;
  float* p = S + (size_t)bh * NCH * HD;
  const float4* src = (const float4*)p;
  float4* dst = (float4*)tile;
#pragma unroll 4
  for (int k = 0; k < (NCH * HD / 4) / 64; k++) dst[k * 64 + tid] = src[k * 64 + tid];
  __syncthreads();
  float run = 0.f;
  for (int c = 0; c < NCH; c++) {
    const float v = tile[c * HD + tid];
    tile[c * HD + tid] = run;
    run += v;
  }
  __syncthreads();
  float4* out = (float4*)p;
#pragma unroll 4
  for (int k = 0; k < (NCH * HD / 4) / 64; k++) out[k * 64 + tid] = dst[k * 64 + tid];
}

// fused exclusive prefix for dots: S2 (LDS-tile column scan) + SA (wave shfl scan, 2/lane)
__global__ __launch_bounds__(64) void prefix_dots(float* __restrict__ S2, float* __restrict__ SA) {
  __shared__ float tile[NCH * HD];          // 32 KB
  const int bh = blockIdx.x, tid = threadIdx.x;
  // SA: 128 chunk sums; lanes hold 2 each
  float* q = SA + (size_t)bh * NCH;
  const float v0 = q[tid], v1 = q[64 + tid];
  float i0 = v0;
#pragma unroll
  for (int off = 1; off < 64; off <<= 1) {
    const float n = __shfl_up(i0, off, 64);
    if (tid >= off) i0 += n;
  }
  const float tot0 = __shfl(i0, 63, 64);
  float i1 = v1;
#pragma unroll
  for (int off = 1; off < 64; off <<= 1) {
    const float n = __shfl_up(i1, off, 64);
    if (tid >= off) i1 += n;
  }
  i1 += tot0;
  q[tid] = i0 - v0;
  q[64 + tid] = i1 - v1;
  // S2 tile scan
  float* p = S2 + (size_t)bh * NCH * HD;
  const float4* src = (const float4*)p;
  float4* dst = (float4*)tile;
#pragma unroll 4
  for (int k = 0; k < (NCH * HD / 4) / 64; k++) dst[k * 64 + tid] = src[k * 64 + tid];
  __syncthreads();
  float run = 0.f;
  for (int c = 0; c < NCH; c++) {
    const float v = tile[c * HD + tid];
    tile[c * HD + tid] = run;
    run += v;
  }
  __syncthreads();
  float4* out = (float4*)p;
#pragma unroll 4
  for (int k = 0; k < (NCH * HD / 4) / 64; k++) out[k * 64 + tid] = dst[k * 64 + tid];
}

// tssa[b,t,h] = temp[h] * sum_d( w_sq / max(cumsum_t(w_sq),1e-12) )
// 16 lanes x 4 d-elems per t-row; 4 chunks per wave (one per 16-lane group).
__global__ __launch_bounds__(64) void tssa_phase3(const bf16* __restrict__ w,
                                                  const float* __restrict__ Sex,
                                                  const float* __restrict__ temp,
                                                  float* __restrict__ tssa) {
  const int g = threadIdx.x >> 4, l = threadIdx.x & 15;
  const int c = blockIdx.x * 4 + g, h = blockIdx.y, b = blockIdx.z;
  const float4 ex = *(const float4*)&Sex[(((size_t)(b * NHh + h) * NCH) + c) * HD + l * 4];
  float a0 = ex.x, a1 = ex.y, a2 = ex.z, a3 = ex.w;
  const bf16* wp = w + ((size_t)(b * Tt + c * CHL)) * Dm + h * HD + l * 4;
  const float tv = temp[h];
  float* op = tssa + ((size_t)(b * Tt + c * CHL)) * NHh + h;
#pragma unroll 8
  for (int i = 0; i < CHL; i++) {
    const ushort4 v = *(const ushort4*)(wp + (size_t)i * Dm);
    const float f0 = b2f(v.x), f1 = b2f(v.y), f2 = b2f(v.z), f3 = b2f(v.w);
    const float s0 = f0 * f0, s1 = f1 * f1, s2 = f2 * f2, s3 = f3 * f3;
    a0 += s0; a1 += s1; a2 += s2; a3 += s3;
    float val = s0 * frcp(fmaxf(a0, 1e-12f)) + s1 * frcp(fmaxf(a1, 1e-12f))
              + s2 * frcp(fmaxf(a2, 1e-12f)) + s3 * frcp(fmaxf(a3, 1e-12f));
    val += __shfl_xor(val, 1, 64);
    val += __shfl_xor(val, 2, 64);
    val += __shfl_xor(val, 4, 64);
    val += __shfl_xor(val, 8, 64);
    if (l == 0) op[(size_t)i * NHh] = tv * val;
  }
}

// softmax over heads; tssa is [b,t,h] (contiguous 16 floats per thread)
__global__ void softmax_heads(const float* __restrict__ tssa, const float* __restrict__ penalty,
                              const float* __restrict__ gamma, float* __restrict__ alpha_f) {
  const int idx = blockIdx.x * blockDim.x + threadIdx.x;  // over B*T
  const int b = idx >> 12;     // T = 4096
  const int t = idx & 4095;
  const float pen = penalty[idx];
  float sc[NHh];
  const float4* tp = (const float4*)(tssa + (size_t)idx * NHh);
#pragma unroll
  for (int q = 0; q < 4; q++) {
    const float4 v = tp[q];
    sc[q * 4 + 0] = v.x; sc[q * 4 + 1] = v.y; sc[q * 4 + 2] = v.z; sc[q * 4 + 3] = v.w;
  }
  float mx = -1e30f;
#pragma unroll
  for (int h = 0; h < NHh; h++) {
    sc[h] -= gamma[h] * pen;
    mx = fmaxf(mx, sc[h]);
  }
  float sum = 0.f;
#pragma unroll
  for (int h = 0; h < NHh; h++) { const float e = __expf(sc[h] - mx); sc[h] = e; sum += e; }
  const float inv = 1.f / sum;
#pragma unroll
  for (int h = 0; h < NHh; h++) {
    alpha_f[((size_t)(b * NHh + h)) * Tt + t] = sc[h] * inv;
  }
}

// chunk sums of w_sq*alpha (vec, per-d) and alpha (scalar)
__global__ __launch_bounds__(64) void dots_phase1(const bf16* __restrict__ w,
                                                  const float* __restrict__ alpha_f,
                                                  float* __restrict__ S2, float* __restrict__ SA) {
  const int g = threadIdx.x >> 4, l = threadIdx.x & 15;
  const int c = blockIdx.x * 4 + g, h = blockIdx.y, b = blockIdx.z;
  const bf16* wp = w + ((size_t)(b * Tt + c * CHL)) * Dm + h * HD + l * 4;
  const float* ap = alpha_f + (size_t)(b * NHh + h) * Tt + c * CHL;
  float a0 = 0.f, a1 = 0.f, a2 = 0.f, a3 = 0.f, acca = 0.f;
#pragma unroll 8
  for (int i = 0; i < CHL; i++) {
    const float a = ap[i];
    const ushort4 v = *(const ushort4*)(wp + (size_t)i * Dm);
    const float f0 = b2f(v.x), f1 = b2f(v.y), f2 = b2f(v.z), f3 = b2f(v.w);
    a0 += f0 * f0 * a; a1 += f1 * f1 * a; a2 += f2 * f2 * a; a3 += f3 * f3 * a;
    acca += a;
  }
  float4 o; o.x = a0; o.y = a1; o.z = a2; o.w = a3;
  *(float4*)&S2[(((size_t)(b * NHh + h) * NCH) + c) * HD + l * 4] = o;
  if (l == 0) SA[(size_t)(b * NHh + h) * NCH + c] = acca;
}

// y'[b,t,h*64+d] = -w * alpha * min(1/(1+dots), 1e4), bf16 (vectorized 4 d/lane)
__global__ __launch_bounds__(64) void y_phase3(const bf16* __restrict__ w,
                                               const float* __restrict__ alpha_f,
                                               const float* __restrict__ S2ex,
                                               const float* __restrict__ SAex,
                                               bf16* __restrict__ yprime) {
  const int g = threadIdx.x >> 4, l = threadIdx.x & 15;
  const int c = blockIdx.x * 4 + g, h = blockIdx.y, b = blockIdx.z;
  const float4 ex = *(const float4*)&S2ex[(((size_t)(b * NHh + h) * NCH) + c) * HD + l * 4];
  float a0 = ex.x, a1 = ex.y, a2 = ex.z, a3 = ex.w;
  float acca = SAex[(size_t)(b * NHh + h) * NCH + c];
  const bf16* wp = w + ((size_t)(b * Tt + c * CHL)) * Dm + h * HD + l * 4;
  const float* ap = alpha_f + (size_t)(b * NHh + h) * Tt + c * CHL;
  bf16* yp = yprime + ((size_t)(b * Tt + c * CHL)) * Dm + h * HD + l * 4;
#pragma unroll 8
  for (int i = 0; i < CHL; i++) {
    const float a = ap[i];
    const ushort4 v = *(const ushort4*)(wp + (size_t)i * Dm);
    const float f0 = b2f(v.x), f1 = b2f(v.y), f2 = b2f(v.z), f3 = b2f(v.w);
    a0 += f0 * f0 * a; a1 += f1 * f1 * a; a2 += f2 * f2 * a; a3 += f3 * f3 * a;
    acca += a;
    const float rinv = frcp(acca + 1e-8f);
    const float at0 = fminf(frcp(1.f + a0 * rinv), 10000.f);
    const float at1 = fminf(frcp(1.f + a1 * rinv), 10000.f);
    const float at2 = fminf(frcp(1.f + a2 * rinv), 10000.f);
    const float at3 = fminf(frcp(1.f + a3 * rinv), 10000.f);
    ushort4 o;
    o.x = __bfloat16_as_ushort(__float2bfloat16(-f0 * a * at0));
    o.y = __bfloat16_as_ushort(__float2bfloat16(-f1 * a * at1));
    o.z = __bfloat16_as_ushort(__float2bfloat16(-f2 * a * at2));
    o.w = __bfloat16_as_ushort(__float2bfloat16(-f3 * a * at3));
    *(ushort4*)(yp + (size_t)i * Dm) = o;
  }
}

extern "C" void kernel_launch(void* const* d_in, const int* in_sizes, int n_in,
                              void* d_out, int out_size, void* d_ws, size_t ws_size,
                              hipStream_t stream) {
  // Reference dtypes: ALL inputs float32, outputs (y, alpha) float32.
  const float* x     = (const float*)d_in[0];
  const float* phi   = (const float*)d_in[1];
  const float* Wattn = (const float*)d_in[2];
  const float* Wproj = (const float*)d_in[3];
  const float* gamma = (const float*)d_in[4];
  const float* temp  = (const float*)d_in[5];

  float* y_out    = (float*)d_out;                          // (B,T,D) fp32
  float* alpha_f  = y_out + (size_t)Bb * Tt * Dm;           // (B,NH,T) fp32

  char* ws = (char*)d_ws;
  bf16*  x_bf   = (bf16*)ws;  ws += (size_t)Bb * Tt * Dm * 2;         // 32 MB
  bf16*  Wa_bf  = (bf16*)ws;  ws += (size_t)Dm * Dm * 2;              // 2 MB
  bf16*  Wp_bf  = (bf16*)ws;  ws += (size_t)Dm * Dm * 2;              // 2 MB
  bf16*  w_bf   = (bf16*)ws;  ws += (size_t)Bb * Tt * Dm * 2;         // 32 MB
  float* tssa   = (float*)ws; ws += (size_t)Bb * Tt * NHh * 4;        // 1 MB  [b,t,h]
  float* pen    = (float*)ws; ws += (size_t)Bb * Tt * 4;              // 64 KB
  float* S1     = (float*)ws; ws += (size_t)Bb * NHh * NCH * HD * 4;  // 2 MB
  float* S2     = (float*)ws; ws += (size_t)Bb * NHh * NCH * HD * 4;  // 2 MB
  float* SA     = (float*)ws; ws += (size_t)Bb * NHh * NCH * 4;       // 32 KB
  bf16*  yprime = x_bf;  // alias: x_bf is dead after GEMM1

  const int M = Bb * Tt, N = Dm, K = Dm;
  dim3 gg(N / 128, M / 128), gb(256);
  dim3 g3(NCH / 4, NHh, Bb), b64(64);

  cast_f32_to_bf16<<<dim3(1024), dim3(256), 0, stream>>>(x, x_bf, Bb * Tt * Dm);
  cast_f32_to_bf16<<<dim3(256), dim3(256), 0, stream>>>(Wattn, Wa_bf, Dm * Dm);
  cast_f32_to_bf16<<<dim3(256), dim3(256), 0, stream>>>(Wproj, Wp_bf, Dm * Dm);

  gemm_bt<true, true><<<gg, gb, 0, stream>>>(x_bf, Wa_bf, (void*)w_bf, S1, M, N, K);
  phi_penalty_kernel<<<dim3(Bb), dim3(1024), 0, stream>>>(phi, pen);
  prefix_vec<<<dim3(Bb * NHh), b64, 0, stream>>>(S1);
  tssa_phase3<<<g3, b64, 0, stream>>>(w_bf, S1, temp, tssa);
  softmax_heads<<<dim3(Bb * Tt / 256), dim3(256), 0, stream>>>(tssa, pen, gamma, alpha_f);
  dots_phase1<<<g3, b64, 0, stream>>>(w_bf, alpha_f, S2, SA);
  prefix_dots<<<dim3(Bb * NHh), b64, 0, stream>>>(S2, SA);
  y_phase3<<<g3, b64, 0, stream>>>(w_bf, alpha_f, S2, SA, yprime);
  gemm_bt<false, false><<<gg, gb, 0, stream>>>(yprime, Wp_bf, (void*)y_out, nullptr, M, N, K);
}

// Round 2
// 264.042 us; speedup vs baseline: 1.2661x; 1.0967x over previous
//
#include <hip/hip_runtime.h>
#include <hip/hip_bf16.h>
#include <stdint.h>

// Problem constants (B,T,D,NH from reference)
#define NHh 16
#define Dm  1024
#define HD  64          // head dim = D/NH
#define Bb  4
#define Tt  4096
#define NCH 128         // chunks along T for the two-pass scans
#define CHL 32          // chunk length (NCH*CHL == Tt)

// 256x256 GEMM tile geometry
#define BM 256
#define BN 256
#define BK 64
#define NKT (Dm / BK)   // 16 K-tiles

using bf16 = __hip_bfloat16;
typedef __attribute__((ext_vector_type(8))) short short8;   // 8 bf16 in 4 VGPRs (MFMA A/B frag)
typedef __attribute__((ext_vector_type(4))) float f32x4;    // MFMA C/D frag

__device__ __forceinline__ float bf2f(bf16 v) { return __bfloat162float(v); }

// bf16 bits -> f32 (exact): bf16 is the high 16 bits of f32
__device__ __forceinline__ float b2f(unsigned short u) {
  union { unsigned int i; float f; } x; x.i = ((unsigned int)u) << 16; return x.f;
}

// fast reciprocal via v_rcp_f32 (~1 ulp; inputs are bf16-derived, tolerance is 1e-2)
__device__ __forceinline__ float frcp(float x) {
  float r; asm("v_rcp_f32 %0, %1" : "=v"(r) : "v"(x)); return r;
}

// async global->LDS, 16B per lane. LDS dest is wave-uniform base + lane*16.
__device__ __forceinline__ void gld_lds16(const void* g, void* l) {
  __builtin_amdgcn_global_load_lds(
      (const __attribute__((address_space(1))) unsigned int*)g,
      (__attribute__((address_space(3))) unsigned int*)l, 16, 0, 0);
}

// fp32 -> bf16 cast, vectorized; n divisible by 4
__global__ void cast_f32_to_bf16(const float* __restrict__ in, bf16* __restrict__ out, int n) {
  const int stride = gridDim.x * blockDim.x;
  for (int i = blockIdx.x * blockDim.x + threadIdx.x; i * 4 < n; i += stride) {
    const float4 v = *(const float4*)(in + (size_t)i * 4);
    ushort4 o;
    o.x = __bfloat16_as_ushort(__float2bfloat16(v.x));
    o.y = __bfloat16_as_ushort(__float2bfloat16(v.y));
    o.z = __bfloat16_as_ushort(__float2bfloat16(v.z));
    o.w = __bfloat16_as_ushort(__float2bfloat16(v.w));
    *(ushort4*)(out + (size_t)i * 4) = o;
  }
}

// ===================== 256x256 deep-pipelined GEMM (8-phase family) ==========
// C[m][n] = sum_k A[m][k] * W[n][k]  (both K-contiguous row-major, bf16)
// 512 threads = 8 waves (2 M-halves x 4 N-quarters), per-wave 128x64 output,
// acc[8][4] f32x4.  Double-buffered 128 KiB LDS (dynamic).  Per K-tile:
//   phase A: ds_read all B frags + A-half0, issue 4 A-stage loads for tile j+1,
//            setprio(1) 32 MFMA setprio(0)
//   phase B: ds_read A-half1, issue 4 B-stage loads, 32 MFMA
//   s_waitcnt vmcnt(0) (cheap: loads were issued a full tile of compute ago),
//   raw s_barrier (NO __syncthreads -> no forced drain at top of tile).
// LDS XOR swizzle (rule #21, both-sides): logical byte P (row-major [256][64]
// bf16, 128 B/row) stored at L = P ^ ((row&7)<<4).  gld_lds writes linearly,
// so the *global source* per lane is inverse-swizzled: issue n, lane l loads
// row n*64+wave*8+(l>>3), col 8*((l&7)^(l>>3)); reads apply the same XOR.
// Read bank check: bank group = 4*((slot)^(row&7)) -> 8 lanes per 4-bank
// group = structural minimum (conflict-free).
// WRITE_S1: fuse per-32-row chunk sums of bf16(w)^2 into the epilogue.
template <bool OUT_BF16, bool WRITE_S1>
__global__ __launch_bounds__(512, 2) void gemm256(const bf16* __restrict__ A,
                                                  const bf16* __restrict__ W,
                                                  void* __restrict__ Cout,
                                                  float* __restrict__ S1,
                                                  int M, int N, int K) {
  extern __shared__ char smem[];   // 131072 B: [buf][A 32K | B 32K]
  const int tid  = threadIdx.x;
  const int lane = tid & 63;
  const int wave = tid >> 6;       // 0..7
  // T1 XCD swizzle: 256 blocks = 8 XCDs x 32; consecutive swz share the A-panel
  const int bid = blockIdx.x;
  const int swz = (bid & 7) * 32 + (bid >> 3);
  const int bn = (swz & 3) * BN;          // N/BN = 4
  const int bm = (swz >> 2) * BM;
  const int wm = (wave >> 2) * 128;       // 2 M-halves
  const int wn = (wave & 3) * 64;         // 4 N-quarters
  const int quad = lane >> 4;
  const int l16  = lane & 15;

  // staging source (per lane, per issue n): see swizzle comment above
  const int srow = wave * 8 + (lane >> 3);               // + n*64
  const int scol = (((lane & 7) ^ (lane >> 3)) << 3);    // elements

  const bf16* Abase = A + (size_t)(bm + srow) * K + scol;
  const bf16* Wbase = W + (size_t)(bn + srow) * K + scol;

  f32x4 acc[8][4] = {};

#define LDSA(buf, n) (smem + (buf) * 65536 + (n) * 8192 + wave * 1024)
#define LDSB(buf, n) (smem + (buf) * 65536 + 32768 + (n) * 8192 + wave * 1024)

#define STAGE_A(buf, n, k0) gld_lds16(Abase + (size_t)(n) * 64 * K + (k0), LDSA(buf, n))
#define STAGE_B(buf, n, k0) gld_lds16(Wbase + (size_t)(n) * 64 * K + (k0), LDSB(buf, n))

  // swizzled ds_read of one 16B fragment
#define LD_FRAG(base, r, s) (*(const short8*)((base) + (size_t)(r) * 128 + ((((s) ^ ((r) & 7))) << 4)))

  // prologue: stage tile 0 into buf 0
#pragma unroll
  for (int n = 0; n < 4; n++) STAGE_A(0, n, 0);
#pragma unroll
  for (int n = 0; n < 4; n++) STAGE_B(0, n, 0);
  asm volatile("s_waitcnt vmcnt(0)" ::: "memory");
  __builtin_amdgcn_s_barrier();
  __builtin_amdgcn_sched_barrier(0);

  for (int j = 0; j < NKT; j++) {
    const int buf = j & 1;
    const char* aL = smem + buf * 65536;
    const char* bL = smem + buf * 65536 + 32768;
    const int k0n = (j + 1) * BK;
    const bool pf = (j + 1 < NKT);

    // ---- phase A: all B frags + A half 0 ----
    short8 bfv[4][2];
#pragma unroll
    for (int nj = 0; nj < 4; nj++) {
      const int r = wn + nj * 16 + l16;
      bfv[nj][0] = LD_FRAG(bL, r, quad);
      bfv[nj][1] = LD_FRAG(bL, r, quad + 4);
    }
    short8 af[4][2];
#pragma unroll
    for (int mi = 0; mi < 4; mi++) {
      const int r = wm + mi * 16 + l16;
      af[mi][0] = LD_FRAG(aL, r, quad);
      af[mi][1] = LD_FRAG(aL, r, quad + 4);
    }
    if (pf) {
      STAGE_A(buf ^ 1, 0, k0n); STAGE_A(buf ^ 1, 1, k0n);
      STAGE_A(buf ^ 1, 2, k0n); STAGE_A(buf ^ 1, 3, k0n);
    }
    __builtin_amdgcn_s_setprio(1);
#pragma unroll
    for (int mi = 0; mi < 4; mi++)
#pragma unroll
      for (int nj = 0; nj < 4; nj++) {
        acc[mi][nj] = __builtin_amdgcn_mfma_f32_16x16x32_bf16(af[mi][0], bfv[nj][0], acc[mi][nj], 0, 0, 0);
        acc[mi][nj] = __builtin_amdgcn_mfma_f32_16x16x32_bf16(af[mi][1], bfv[nj][1], acc[mi][nj], 0, 0, 0);
      }
    __builtin_amdgcn_s_setprio(0);
    __builtin_amdgcn_sched_barrier(0);

    // ---- phase B: A half 1 ----
#pragma unroll
    for (int mi = 0; mi < 4; mi++) {
      const int r = wm + 64 + mi * 16 + l16;
      af[mi][0] = LD_FRAG(aL, r, quad);
      af[mi][1] = LD_FRAG(aL, r, quad + 4);
    }
    if (pf) {
      STAGE_B(buf ^ 1, 0, k0n); STAGE_B(buf ^ 1, 1, k0n);
      STAGE_B(buf ^ 1, 2, k0n); STAGE_B(buf ^ 1, 3, k0n);
    }
    __builtin_amdgcn_s_setprio(1);
#pragma unroll
    for (int mi = 0; mi < 4; mi++)
#pragma unroll
      for (int nj = 0; nj < 4; nj++) {
        acc[mi + 4][nj] = __builtin_amdgcn_mfma_f32_16x16x32_bf16(af[mi][0], bfv[nj][0], acc[mi + 4][nj], 0, 0, 0);
        acc[mi + 4][nj] = __builtin_amdgcn_mfma_f32_16x16x32_bf16(af[mi][1], bfv[nj][1], acc[mi + 4][nj], 0, 0, 0);
      }
    __builtin_amdgcn_s_setprio(0);

    // tile boundary: own stage loads landed (issued a full tile ago), then barrier
    asm volatile("s_waitcnt vmcnt(0)" ::: "memory");
    __builtin_amdgcn_s_barrier();
    __builtin_amdgcn_sched_barrier(0);
  }

  // C/D layout (HW-verified): col = lane&15, row = (lane>>4)*4 + reg
#pragma unroll
  for (int nj = 0; nj < 4; nj++) {
    const int col = bn + wn + nj * 16 + l16;
    if constexpr (OUT_BF16) {
      float ss0 = 0.f, ss1 = 0.f, ss2 = 0.f, ss3 = 0.f;   // 4 chunks of 32 rows
#pragma unroll
      for (int mi = 0; mi < 8; mi++) {
        float csum = 0.f;
#pragma unroll
        for (int r = 0; r < 4; r++) {
          const int row = bm + wm + mi * 16 + quad * 4 + r;
          const bf16 hv = __float2bfloat16(acc[mi][nj][r]);
          ((bf16*)Cout)[(size_t)row * N + col] = hv;
          if constexpr (WRITE_S1) { const float fv = bf2f(hv); csum += fv * fv; }
        }
        if constexpr (WRITE_S1) {
          if (mi < 2) ss0 += csum;
          else if (mi < 4) ss1 += csum;
          else if (mi < 6) ss2 += csum;
          else ss3 += csum;
        }
      }
      if constexpr (WRITE_S1) {
        ss0 += __shfl_xor(ss0, 16, 64); ss0 += __shfl_xor(ss0, 32, 64);
        ss1 += __shfl_xor(ss1, 16, 64); ss1 += __shfl_xor(ss1, 32, 64);
        ss2 += __shfl_xor(ss2, 16, 64); ss2 += __shfl_xor(ss2, 32, 64);
        ss3 += __shfl_xor(ss3, 16, 64); ss3 += __shfl_xor(ss3, 32, 64);
        if (quad == 0) {
          const int h = col >> 6, d = col & 63;
          const int r0 = bm + wm;                    // first row of this wave's 128-row block
          const int b  = r0 >> 12;                   // / Tt
          const int c0 = (r0 & (Tt - 1)) >> 5;       // / CHL (=32)
          float* s1p = S1 + (((size_t)(b * NHh + h) * NCH) + c0) * HD + d;
          s1p[0]      = ss0;
          s1p[HD]     = ss1;
          s1p[2 * HD] = ss2;
          s1p[3 * HD] = ss3;
        }
      }
    } else {
#pragma unroll
      for (int mi = 0; mi < 8; mi++)
#pragma unroll
        for (int r = 0; r < 4; r++) {
          const int row = bm + wm + mi * 16 + quad * 4 + r;
          ((float*)Cout)[(size_t)row * N + col] = acc[mi][nj][r];
        }
    }
  }
#undef LDSA
#undef LDSB
#undef STAGE_A
#undef STAGE_B
#undef LD_FRAG
}

// penalty[b,t] = (phi[b,t] - cumsum(phi)[b,t]/(t+1))^2 ; 1024-thread block scan per batch
__global__ __launch_bounds__(1024) void phi_penalty_kernel(const float* __restrict__ phi,
                                                           float* __restrict__ penalty) {
  const int b = blockIdx.x;
  const int tid = threadIdx.x;            // 1024
  const int lane = tid & 63, wid = tid >> 6;   // 16 waves
  __shared__ float wsum[16];
  __shared__ float carry_s;
  if (tid == 0) carry_s = 0.f;
  __syncthreads();
  for (int r = 0; r < Tt / 1024; r++) {
    const int t = r * 1024 + tid;
    const float v = phi[b * Tt + t];
    float incl = v;
#pragma unroll
    for (int off = 1; off < 64; off <<= 1) {
      float n = __shfl_up(incl, off, 64);
      if (lane >= off) incl += n;
    }
    if (lane == 63) wsum[wid] = incl;
    __syncthreads();
    float woff = carry_s;
    for (int wpre = 0; wpre < wid; wpre++) woff += wsum[wpre];
    const float csum = woff + incl;
    const float mean = csum / (float)(t + 1);
    const float dphi = v - mean;
    penalty[b * Tt + t] = dphi * dphi;
    __syncthreads();
    if (tid == 0) {
      float s = 0.f;
      for (int w = 0; w < 16; w++) s += wsum[w];
      carry_s += s;
    }
    __syncthreads();
  }
}

// in-place exclusive prefix over chunks, per (b,h,d) — LDS-tile version.
__global__ __launch_bounds__(64) void prefix_vec(float* __restrict__ S) {
  __shared__ float tile[NCH * HD];          // 32 KB
  const int bh = blockIdx.x, tid = threadIdx.x;
  float* p = S + (size_t)bh * NCH * HD;
  const float4* src = (const float4*)p;
  float4* dst = (float4*)tile;
#pragma unroll 4
  for (int k = 0; k < (NCH * HD / 4) / 64; k++) dst[k * 64 + tid] = src[k * 64 + tid];
  __syncthreads();
  float run = 0.f;
  for (int c = 0; c < NCH; c++) {
    const float v = tile[c * HD + tid];
    tile[c * HD + tid] = run;
    run += v;
  }
  __syncthreads();
  float4* out = (float4*)p;
#pragma unroll 4
  for (int k = 0; k < (NCH * HD / 4) / 64; k++) out[k * 64 + tid] = dst[k * 64 + tid];
}

// fused exclusive prefix for dots: S2 (LDS-tile column scan) + SA (wave shfl scan, 2/lane)
__global__ __launch_bounds__(64) void prefix_dots(float* __restrict__ S2, float* __restrict__ SA) {
  __shared__ float tile[NCH * HD];          // 32 KB
  const int bh = blockIdx.x, tid = threadIdx.x;
  float* q = SA + (size_t)bh * NCH;
  const float v0 = q[tid], v1 = q[64 + tid];
  float i0 = v0;
#pragma unroll
  for (int off = 1; off < 64; off <<= 1) {
    const float n = __shfl_up(i0, off, 64);
    if (tid >= off) i0 += n;
  }
  const float tot0 = __shfl(i0, 63, 64);
  float i1 = v1;
#pragma unroll
  for (int off = 1; off < 64; off <<= 1) {
    const float n = __shfl_up(i1, off, 64);
    if (tid >= off) i1 += n;
  }
  i1 += tot0;
  q[tid] = i0 - v0;
  q[64 + tid] = i1 - v1;
  float* p = S2 + (size_t)bh * NCH * HD;
  const float4* src = (const float4*)p;
  float4* dst = (float4*)tile;
#pragma unroll 4
  for (int k = 0; k < (NCH * HD / 4) / 64; k++) dst[k * 64 + tid] = src[k * 64 + tid];
  __syncthreads();
  float run = 0.f;
  for (int c = 0; c < NCH; c++) {
    const float v = tile[c * HD + tid];
    tile[c * HD + tid] = run;
    run += v;
  }
  __syncthreads();
  float4* out = (float4*)p;
#pragma unroll 4
  for (int k = 0; k < (NCH * HD / 4) / 64; k++) out[k * 64 + tid] = dst[k * 64 + tid];
}

// tssa[b,t,h] = temp[h] * sum_d( w_sq / max(cumsum_t(w_sq),1e-12) )
__global__ __launch_bounds__(64) void tssa_phase3(const bf16* __restrict__ w,
                                                  const float* __restrict__ Sex,
                                                  const float* __restrict__ temp,
                                                  float* __restrict__ tssa) {
  const int g = threadIdx.x >> 4, l = threadIdx.x & 15;
  const int c = blockIdx.x * 4 + g, h = blockIdx.y, b = blockIdx.z;
  const float4 ex = *(const float4*)&Sex[(((size_t)(b * NHh + h) * NCH) + c) * HD + l * 4];
  float a0 = ex.x, a1 = ex.y, a2 = ex.z, a3 = ex.w;
  const bf16* wp = w + ((size_t)(b * Tt + c * CHL)) * Dm + h * HD + l * 4;
  const float tv = temp[h];
  float* op = tssa + ((size_t)(b * Tt + c * CHL)) * NHh + h;
#pragma unroll 8
  for (int i = 0; i < CHL; i++) {
    const ushort4 v = *(const ushort4*)(wp + (size_t)i * Dm);
    const float f0 = b2f(v.x), f1 = b2f(v.y), f2 = b2f(v.z), f3 = b2f(v.w);
    const float s0 = f0 * f0, s1 = f1 * f1, s2 = f2 * f2, s3 = f3 * f3;
    a0 += s0; a1 += s1; a2 += s2; a3 += s3;
    float val = s0 * frcp(fmaxf(a0, 1e-12f)) + s1 * frcp(fmaxf(a1, 1e-12f))
              + s2 * frcp(fmaxf(a2, 1e-12f)) + s3 * frcp(fmaxf(a3, 1e-12f));
    val += __shfl_xor(val, 1, 64);
    val += __shfl_xor(val, 2, 64);
    val += __shfl_xor(val, 4, 64);
    val += __shfl_xor(val, 8, 64);
    if (l == 0) op[(size_t)i * NHh] = tv * val;
  }
}

// softmax over heads; tssa is [b,t,h] (contiguous 16 floats per thread)
__global__ void softmax_heads(const float* __restrict__ tssa, const float* __restrict__ penalty,
                              const float* __restrict__ gamma, float* __restrict__ alpha_f) {
  const int idx = blockIdx.x * blockDim.x + threadIdx.x;  // over B*T
  const int b = idx >> 12;     // T = 4096
  const int t = idx & 4095;
  const float pen = penalty[idx];
  float sc[NHh];
  const float4* tp = (const float4*)(tssa + (size_t)idx * NHh);
#pragma unroll
  for (int q = 0; q < 4; q++) {
    const float4 v = tp[q];
    sc[q * 4 + 0] = v.x; sc[q * 4 + 1] = v.y; sc[q * 4 + 2] = v.z; sc[q * 4 + 3] = v.w;
  }
  float mx = -1e30f;
#pragma unroll
  for (int h = 0; h < NHh; h++) {
    sc[h] -= gamma[h] * pen;
    mx = fmaxf(mx, sc[h]);
  }
  float sum = 0.f;
#pragma unroll
  for (int h = 0; h < NHh; h++) { const float e = __expf(sc[h] - mx); sc[h] = e; sum += e; }
  const float inv = 1.f / sum;
#pragma unroll
  for (int h = 0; h < NHh; h++) {
    alpha_f[((size_t)(b * NHh + h)) * Tt + t] = sc[h] * inv;
  }
}

// chunk sums of w_sq*alpha (vec, per-d) and alpha (scalar)
__global__ __launch_bounds__(64) void dots_phase1(const bf16* __restrict__ w,
                                                  const float* __restrict__ alpha_f,
                                                  float* __restrict__ S2, float* __restrict__ SA) {
  const int g = threadIdx.x >> 4, l = threadIdx.x & 15;
  const int c = blockIdx.x * 4 + g, h = blockIdx.y, b = blockIdx.z;
  const bf16* wp = w + ((size_t)(b * Tt + c * CHL)) * Dm + h * HD + l * 4;
  const float* ap = alpha_f + (size_t)(b * NHh + h) * Tt + c * CHL;
  float a0 = 0.f, a1 = 0.f, a2 = 0.f, a3 = 0.f, acca = 0.f;
#pragma unroll 8
  for (int i = 0; i < CHL; i++) {
    const float a = ap[i];
    const ushort4 v = *(const ushort4*)(wp + (size_t)i * Dm);
    const float f0 = b2f(v.x), f1 = b2f(v.y), f2 = b2f(v.z), f3 = b2f(v.w);
    a0 += f0 * f0 * a; a1 += f1 * f1 * a; a2 += f2 * f2 * a; a3 += f3 * f3 * a;
    acca += a;
  }
  float4 o; o.x = a0; o.y = a1; o.z = a2; o.w = a3;
  *(float4*)&S2[(((size_t)(b * NHh + h) * NCH) + c) * HD + l * 4] = o;
  if (l == 0) SA[(size_t)(b * NHh + h) * NCH + c] = acca;
}

// y'[b,t,h*64+d] = -w * alpha * min(1/(1+dots), 1e4), bf16 (vectorized 4 d/lane)
__global__ __launch_bounds__(64) void y_phase3(const bf16* __restrict__ w,
                                               const float* __restrict__ alpha_f,
                                               const float* __restrict__ S2ex,
                                               const float* __restrict__ SAex,
                                               bf16* __restrict__ yprime) {
  const int g = threadIdx.x >> 4, l = threadIdx.x & 15;
  const int c = blockIdx.x * 4 + g, h = blockIdx.y, b = blockIdx.z;
  const float4 ex = *(const float4*)&S2ex[(((size_t)(b * NHh + h) * NCH) + c) * HD + l * 4];
  float a0 = ex.x, a1 = ex.y, a2 = ex.z, a3 = ex.w;
  float acca = SAex[(size_t)(b * NHh + h) * NCH + c];
  const bf16* wp = w + ((size_t)(b * Tt + c * CHL)) * Dm + h * HD + l * 4;
  const float* ap = alpha_f + (size_t)(b * NHh + h) * Tt + c * CHL;
  bf16* yp = yprime + ((size_t)(b * Tt + c * CHL)) * Dm + h * HD + l * 4;
#pragma unroll 8
  for (int i = 0; i < CHL; i++) {
    const float a = ap[i];
    const ushort4 v = *(const ushort4*)(wp + (size_t)i * Dm);
    const float f0 = b2f(v.x), f1 = b2f(v.y), f2 = b2f(v.z), f3 = b2f(v.w);
    a0 += f0 * f0 * a; a1 += f1 * f1 * a; a2 += f2 * f2 * a; a3 += f3 * f3 * a;
    acca += a;
    const float rinv = frcp(acca + 1e-8f);
    const float at0 = fminf(frcp(1.f + a0 * rinv), 10000.f);
    const float at1 = fminf(frcp(1.f + a1 * rinv), 10000.f);
    const float at2 = fminf(frcp(1.f + a2 * rinv), 10000.f);
    const float at3 = fminf(frcp(1.f + a3 * rinv), 10000.f);
    ushort4 o;
    o.x = __bfloat16_as_ushort(__float2bfloat16(-f0 * a * at0));
    o.y = __bfloat16_as_ushort(__float2bfloat16(-f1 * a * at1));
    o.z = __bfloat16_as_ushort(__float2bfloat16(-f2 * a * at2));
    o.w = __bfloat16_as_ushort(__float2bfloat16(-f3 * a * at3));
    *(ushort4*)(yp + (size_t)i * Dm) = o;
  }
}

extern "C" void kernel_launch(void* const* d_in, const int* in_sizes, int n_in,
                              void* d_out, int out_size, void* d_ws, size_t ws_size,
                              hipStream_t stream) {
  const float* x     = (const float*)d_in[0];
  const float* phi   = (const float*)d_in[1];
  const float* Wattn = (const float*)d_in[2];
  const float* Wproj = (const float*)d_in[3];
  const float* gamma = (const float*)d_in[4];
  const float* temp  = (const float*)d_in[5];

  float* y_out    = (float*)d_out;                          // (B,T,D) fp32
  float* alpha_f  = y_out + (size_t)Bb * Tt * Dm;           // (B,NH,T) fp32

  char* ws = (char*)d_ws;
  bf16*  x_bf   = (bf16*)ws;  ws += (size_t)Bb * Tt * Dm * 2;         // 32 MB
  bf16*  Wa_bf  = (bf16*)ws;  ws += (size_t)Dm * Dm * 2;              // 2 MB
  bf16*  Wp_bf  = (bf16*)ws;  ws += (size_t)Dm * Dm * 2;              // 2 MB
  bf16*  w_bf   = (bf16*)ws;  ws += (size_t)Bb * Tt * Dm * 2;         // 32 MB
  float* tssa   = (float*)ws; ws += (size_t)Bb * Tt * NHh * 4;        // 1 MB  [b,t,h]
  float* pen    = (float*)ws; ws += (size_t)Bb * Tt * 4;              // 64 KB
  float* S1     = (float*)ws; ws += (size_t)Bb * NHh * NCH * HD * 4;  // 2 MB
  float* S2     = (float*)ws; ws += (size_t)Bb * NHh * NCH * HD * 4;  // 2 MB
  float* SA     = (float*)ws; ws += (size_t)Bb * NHh * NCH * 4;       // 32 KB
  bf16*  yprime = x_bf;  // alias: x_bf is dead after GEMM1

  static int attr_done = 0;
  if (!attr_done) {
    hipFuncSetAttribute((const void*)gemm256<true, true>,
                        hipFuncAttributeMaxDynamicSharedMemorySize, 131072);
    hipFuncSetAttribute((const void*)gemm256<false, false>,
                        hipFuncAttributeMaxDynamicSharedMemorySize, 131072);
    attr_done = 1;
  }

  const int M = Bb * Tt, N = Dm, K = Dm;
  dim3 gg((M / BM) * (N / BN)), gb(512);
  dim3 g3(NCH / 4, NHh, Bb), b64(64);

  cast_f32_to_bf16<<<dim3(1024), dim3(256), 0, stream>>>(x, x_bf, Bb * Tt * Dm);
  cast_f32_to_bf16<<<dim3(256), dim3(256), 0, stream>>>(Wattn, Wa_bf, Dm * Dm);
  cast_f32_to_bf16<<<dim3(256), dim3(256), 0, stream>>>(Wproj, Wp_bf, Dm * Dm);

  gemm256<true, true><<<gg, gb, 131072, stream>>>(x_bf, Wa_bf, (void*)w_bf, S1, M, N, K);
  phi_penalty_kernel<<<dim3(Bb), dim3(1024), 0, stream>>>(phi, pen);
  prefix_vec<<<dim3(Bb * NHh), b64, 0, stream>>>(S1);
  tssa_phase3<<<g3, b64, 0, stream>>>(w_bf, S1, temp, tssa);
  softmax_heads<<<dim3(Bb * Tt / 256), dim3(256), 0, stream>>>(tssa, pen, gamma, alpha_f);
  dots_phase1<<<g3, b64, 0, stream>>>(w_bf, alpha_f, S2, SA);
  prefix_dots<<<dim3(Bb * NHh), b64, 0, stream>>>(S2, SA);
  y_phase3<<<g3, b64, 0, stream>>>(w_bf, alpha_f, S2, SA, yprime);
  gemm256<false, false><<<gg, gb, 131072, stream>>>(yprime, Wp_bf, (void*)y_out, nullptr, M, N, K);
}

// Round 3
// 260.761 us; speedup vs baseline: 1.2820x; 1.0126x over previous
//
#include <hip/hip_runtime.h>
#include <hip/hip_bf16.h>
#include <stdint.h>

// Problem constants (B,T,D,NH from reference)
#define NHh 16
#define Dm  1024
#define HD  64          // head dim = D/NH
#define Bb  4
#define Tt  4096
#define NCH 128         // chunks along T for the two-pass scans
#define CHL 32          // chunk length (NCH*CHL == Tt)

// 256x256 GEMM tile geometry
#define BM 256
#define BN 256
#define BK 64
#define NKT (Dm / BK)   // 16 K-tiles

using bf16 = __hip_bfloat16;
typedef __attribute__((ext_vector_type(8))) short short8;   // 8 bf16 in 4 VGPRs (MFMA A/B frag)
typedef __attribute__((ext_vector_type(4))) float f32x4;    // MFMA C/D frag

__device__ __forceinline__ float bf2f(bf16 v) { return __bfloat162float(v); }

// bf16 bits -> f32 (exact): bf16 is the high 16 bits of f32
__device__ __forceinline__ float b2f(unsigned short u) {
  union { unsigned int i; float f; } x; x.i = ((unsigned int)u) << 16; return x.f;
}

// fast reciprocal via v_rcp_f32 (~1 ulp; inputs are bf16-derived, tolerance is 1e-2)
__device__ __forceinline__ float frcp(float x) {
  float r; asm("v_rcp_f32 %0, %1" : "=v"(r) : "v"(x)); return r;
}

// async global->LDS, 16B per lane. LDS dest is wave-uniform base + lane*16.
__device__ __forceinline__ void gld_lds16(const void* g, void* l) {
  __builtin_amdgcn_global_load_lds(
      (const __attribute__((address_space(1))) unsigned int*)g,
      (__attribute__((address_space(3))) unsigned int*)l, 16, 0, 0);
}

// fp32 -> bf16 cast, vectorized; n divisible by 4
__global__ void cast_f32_to_bf16(const float* __restrict__ in, bf16* __restrict__ out, int n) {
  const int stride = gridDim.x * blockDim.x;
  for (int i = blockIdx.x * blockDim.x + threadIdx.x; i * 4 < n; i += stride) {
    const float4 v = *(const float4*)(in + (size_t)i * 4);
    ushort4 o;
    o.x = __bfloat16_as_ushort(__float2bfloat16(v.x));
    o.y = __bfloat16_as_ushort(__float2bfloat16(v.y));
    o.z = __bfloat16_as_ushort(__float2bfloat16(v.z));
    o.w = __bfloat16_as_ushort(__float2bfloat16(v.w));
    *(ushort4*)(out + (size_t)i * 4) = o;
  }
}

// ============== 256x256 GEMM, counted-vmcnt 2x-phase pipeline (T3+T4) ========
// C[m][n] = sum_k A[m][k] * W[n][k]  (both K-contiguous row-major, bf16)
// 512 threads = 8 waves as 4M x 2N; per-wave output 64x128 -> acc[4][8].
// Phases split by N-half so read-sets partition by staged slab:
//   P1 reads: A rows all (8 frag reads) + B rows {0-63, 128-191} (8 reads)
//   P2 reads: B rows {64-127, 192-255} (8 reads)
// Staging of tile t+1 into the other buffer:
//   P1 issues 6 slabs: A0,A1,A2,A3 + B0(rows 0-63), B2(rows 128-191)
//   P2 issues 2 slabs: B1(rows 64-127), B3(rows 192-255)
// Counted waits (never vmcnt(0) in steady state):
//   end-P1: vmcnt(6)  -> retires prev-P2's 2 slabs (B1,B3 of current tile)
//   end-P2: vmcnt(2)  -> retires this-P1's 6 slabs (needed by next P1)
// vmcnt is per-wave and placed BEFORE s_barrier, so after the barrier every
// wave's contribution to the staged slabs has landed (cross-wave handoff OK).
// LDS XOR swizzle (both-sides, rule #21): logical [256][64] bf16 rows of
// 128 B; byte P stored at P ^ ((row&7)<<4); gld_lds dest is linear so the
// global source per lane is inverse-swizzled; reads apply the same XOR.
// WRITE_S1: fuse per-32-row chunk sums of bf16(w)^2 into the epilogue.
template <bool OUT_BF16, bool WRITE_S1>
__global__ __launch_bounds__(512, 2) void gemm256(const bf16* __restrict__ A,
                                                  const bf16* __restrict__ W,
                                                  void* __restrict__ Cout,
                                                  float* __restrict__ S1,
                                                  int M, int N, int K) {
  extern __shared__ char smem[];   // 131072 B: [buf][A 32K | B 32K]
  const int tid  = threadIdx.x;
  const int lane = tid & 63;
  const int wave = tid >> 6;       // 0..7
  // T1 XCD swizzle: 256 blocks = 8 XCDs x 32; consecutive swz share the A-panel
  const int bid = blockIdx.x;
  const int swz = (bid & 7) * 32 + (bid >> 3);
  const int bn = (swz & 3) * BN;          // N/BN = 4
  const int bm = (swz >> 2) * BM;
  const int wm = (wave >> 1) * 64;        // 4 M bands of 64 rows
  const int wn = (wave & 1) * 128;        // 2 N halves of 128 cols
  const int quad = lane >> 4;
  const int l16  = lane & 15;

  // staging source (per lane, per slab n): inverse-swizzled global address
  const int srow = wave * 8 + (lane >> 3);               // + n*64
  const int scol = (((lane & 7) ^ (lane >> 3)) << 3);    // elements

  const bf16* Abase = A + (size_t)(bm + srow) * K + scol;
  const bf16* Wbase = W + (size_t)(bn + srow) * K + scol;

  f32x4 acc[4][8] = {};

#define SLAB_A(buf, n) (smem + (buf) * 65536 + (n) * 8192 + wave * 1024)
#define SLAB_B(buf, n) (smem + (buf) * 65536 + 32768 + (n) * 8192 + wave * 1024)
#define STAGE_A(buf, n, k0) gld_lds16(Abase + (size_t)(n) * 64 * K + (k0), SLAB_A(buf, n))
#define STAGE_B(buf, n, k0) gld_lds16(Wbase + (size_t)(n) * 64 * K + (k0), SLAB_B(buf, n))
  // swizzled ds_read of one 16B fragment (r = row 0..255, s = 16B slot 0..7)
#define LD_FRAG(base, r, s) (*(const short8*)((base) + (size_t)(r) * 128 + ((((s) ^ ((r) & 7))) << 4)))

  // prologue: stage tile 0 fully into buf 0
  STAGE_A(0, 0, 0); STAGE_A(0, 1, 0); STAGE_A(0, 2, 0); STAGE_A(0, 3, 0);
  STAGE_B(0, 0, 0); STAGE_B(0, 1, 0); STAGE_B(0, 2, 0); STAGE_B(0, 3, 0);
  asm volatile("s_waitcnt vmcnt(0)" ::: "memory");
  __builtin_amdgcn_s_barrier();
  __builtin_amdgcn_sched_barrier(0);

  short8 af[4][2], bfv[4][2];
  for (int t = 0; t < NKT; t++) {
    const int buf = t & 1;
    const char* aL = smem + buf * 65536;
    const char* bL = aL + 32768;
    const int k0n = (t + 1) * BK;
    const bool pf = (t + 1 < NKT);

    // ---- P1: stage 6 slabs (t+1), read A-all + B lower-halves, MFMA nj 0-3
    if (pf) {
      STAGE_A(buf ^ 1, 0, k0n); STAGE_A(buf ^ 1, 1, k0n);
      STAGE_A(buf ^ 1, 2, k0n); STAGE_A(buf ^ 1, 3, k0n);
      STAGE_B(buf ^ 1, 0, k0n); STAGE_B(buf ^ 1, 2, k0n);
    }
#pragma unroll
    for (int mi = 0; mi < 4; mi++) {
      const int r = wm + mi * 16 + l16;
      af[mi][0] = LD_FRAG(aL, r, quad);
      af[mi][1] = LD_FRAG(aL, r, quad + 4);
    }
#pragma unroll
    for (int nj = 0; nj < 4; nj++) {
      const int r = wn + nj * 16 + l16;
      bfv[nj][0] = LD_FRAG(bL, r, quad);
      bfv[nj][1] = LD_FRAG(bL, r, quad + 4);
    }
    __builtin_amdgcn_s_setprio(1);
#pragma unroll
    for (int mi = 0; mi < 4; mi++)
#pragma unroll
      for (int nj = 0; nj < 4; nj++) {
        acc[mi][nj] = __builtin_amdgcn_mfma_f32_16x16x32_bf16(af[mi][0], bfv[nj][0], acc[mi][nj], 0, 0, 0);
        acc[mi][nj] = __builtin_amdgcn_mfma_f32_16x16x32_bf16(af[mi][1], bfv[nj][1], acc[mi][nj], 0, 0, 0);
      }
    __builtin_amdgcn_s_setprio(0);
    if (pf) { asm volatile("s_waitcnt vmcnt(6)" ::: "memory"); }
    else    { asm volatile("s_waitcnt vmcnt(0)" ::: "memory"); }
    __builtin_amdgcn_s_barrier();
    __builtin_amdgcn_sched_barrier(0);

    // ---- P2: stage 2 slabs (t+1), read B upper-halves, MFMA nj 4-7
    if (pf) { STAGE_B(buf ^ 1, 1, k0n); STAGE_B(buf ^ 1, 3, k0n); }
#pragma unroll
    for (int nj = 0; nj < 4; nj++) {
      const int r = wn + 64 + nj * 16 + l16;
      bfv[nj][0] = LD_FRAG(bL, r, quad);
      bfv[nj][1] = LD_FRAG(bL, r, quad + 4);
    }
    __builtin_amdgcn_s_setprio(1);
#pragma unroll
    for (int mi = 0; mi < 4; mi++)
#pragma unroll
      for (int nj = 0; nj < 4; nj++) {
        acc[mi][nj + 4] = __builtin_amdgcn_mfma_f32_16x16x32_bf16(af[mi][0], bfv[nj][0], acc[mi][nj + 4], 0, 0, 0);
        acc[mi][nj + 4] = __builtin_amdgcn_mfma_f32_16x16x32_bf16(af[mi][1], bfv[nj][1], acc[mi][nj + 4], 0, 0, 0);
      }
    __builtin_amdgcn_s_setprio(0);
    asm volatile("s_waitcnt vmcnt(2)" ::: "memory");
    __builtin_amdgcn_s_barrier();
    __builtin_amdgcn_sched_barrier(0);
  }

  // C/D layout (HW-verified): col = lane&15, row = (lane>>4)*4 + reg
#pragma unroll
  for (int nj = 0; nj < 8; nj++) {
    const int col = bn + wn + nj * 16 + l16;
    if constexpr (OUT_BF16) {
      float ss0 = 0.f, ss1 = 0.f;   // two 32-row chunks of this wave's 64-row band
#pragma unroll
      for (int mi = 0; mi < 4; mi++) {
        float csum = 0.f;
#pragma unroll
        for (int r = 0; r < 4; r++) {
          const int row = bm + wm + mi * 16 + quad * 4 + r;
          const bf16 hv = __float2bfloat16(acc[mi][nj][r]);
          ((bf16*)Cout)[(size_t)row * N + col] = hv;
          if constexpr (WRITE_S1) { const float fv = bf2f(hv); csum += fv * fv; }
        }
        if constexpr (WRITE_S1) { if (mi < 2) ss0 += csum; else ss1 += csum; }
      }
      if constexpr (WRITE_S1) {
        ss0 += __shfl_xor(ss0, 16, 64); ss0 += __shfl_xor(ss0, 32, 64);
        ss1 += __shfl_xor(ss1, 16, 64); ss1 += __shfl_xor(ss1, 32, 64);
        if (quad == 0) {
          const int h = col >> 6, d = col & 63;
          const int r0 = bm + wm;                    // first row of this wave's band
          const int b  = r0 >> 12;                   // / Tt
          const int c0 = (r0 & (Tt - 1)) >> 5;       // / CHL (=32)
          float* s1p = S1 + (((size_t)(b * NHh + h) * NCH) + c0) * HD + d;
          s1p[0]  = ss0;
          s1p[HD] = ss1;
        }
      }
    } else {
#pragma unroll
      for (int mi = 0; mi < 4; mi++)
#pragma unroll
        for (int r = 0; r < 4; r++) {
          const int row = bm + wm + mi * 16 + quad * 4 + r;
          ((float*)Cout)[(size_t)row * N + col] = acc[mi][nj][r];
        }
    }
  }
#undef SLAB_A
#undef SLAB_B
#undef STAGE_A
#undef STAGE_B
#undef LD_FRAG
}

// penalty[b,t] = (phi[b,t] - cumsum(phi)[b,t]/(t+1))^2 ; 1024-thread block scan per batch
__global__ __launch_bounds__(1024) void phi_penalty_kernel(const float* __restrict__ phi,
                                                           float* __restrict__ penalty) {
  const int b = blockIdx.x;
  const int tid = threadIdx.x;            // 1024
  const int lane = tid & 63, wid = tid >> 6;   // 16 waves
  __shared__ float wsum[16];
  __shared__ float carry_s;
  if (tid == 0) carry_s = 0.f;
  __syncthreads();
  for (int r = 0; r < Tt / 1024; r++) {
    const int t = r * 1024 + tid;
    const float v = phi[b * Tt + t];
    float incl = v;
#pragma unroll
    for (int off = 1; off < 64; off <<= 1) {
      float n = __shfl_up(incl, off, 64);
      if (lane >= off) incl += n;
    }
    if (lane == 63) wsum[wid] = incl;
    __syncthreads();
    float woff = carry_s;
    for (int wpre = 0; wpre < wid; wpre++) woff += wsum[wpre];
    const float csum = woff + incl;
    const float mean = csum / (float)(t + 1);
    const float dphi = v - mean;
    penalty[b * Tt + t] = dphi * dphi;
    __syncthreads();
    if (tid == 0) {
      float s = 0.f;
      for (int w = 0; w < 16; w++) s += wsum[w];
      carry_s += s;
    }
    __syncthreads();
  }
}

// in-place exclusive prefix over chunks, per (b,h,d) — LDS-tile version.
__global__ __launch_bounds__(64) void prefix_vec(float* __restrict__ S) {
  __shared__ float tile[NCH * HD];          // 32 KB
  const int bh = blockIdx.x, tid = threadIdx.x;
  float* p = S + (size_t)bh * NCH * HD;
  const float4* src = (const float4*)p;
  float4* dst = (float4*)tile;
#pragma unroll 4
  for (int k = 0; k < (NCH * HD / 4) / 64; k++) dst[k * 64 + tid] = src[k * 64 + tid];
  __syncthreads();
  float run = 0.f;
  for (int c = 0; c < NCH; c++) {
    const float v = tile[c * HD + tid];
    tile[c * HD + tid] = run;
    run += v;
  }
  __syncthreads();
  float4* out = (float4*)p;
#pragma unroll 4
  for (int k = 0; k < (NCH * HD / 4) / 64; k++) out[k * 64 + tid] = dst[k * 64 + tid];
}

// fused exclusive prefix for dots: S2 (LDS-tile column scan) + SA (wave shfl scan, 2/lane)
__global__ __launch_bounds__(64) void prefix_dots(float* __restrict__ S2, float* __restrict__ SA) {
  __shared__ float tile[NCH * HD];          // 32 KB
  const int bh = blockIdx.x, tid = threadIdx.x;
  float* q = SA + (size_t)bh * NCH;
  const float v0 = q[tid], v1 = q[64 + tid];
  float i0 = v0;
#pragma unroll
  for (int off = 1; off < 64; off <<= 1) {
    const float n = __shfl_up(i0, off, 64);
    if (tid >= off) i0 += n;
  }
  const float tot0 = __shfl(i0, 63, 64);
  float i1 = v1;
#pragma unroll
  for (int off = 1; off < 64; off <<= 1) {
    const float n = __shfl_up(i1, off, 64);
    if (tid >= off) i1 += n;
  }
  i1 += tot0;
  q[tid] = i0 - v0;
  q[64 + tid] = i1 - v1;
  float* p = S2 + (size_t)bh * NCH * HD;
  const float4* src = (const float4*)p;
  float4* dst = (float4*)tile;
#pragma unroll 4
  for (int k = 0; k < (NCH * HD / 4) / 64; k++) dst[k * 64 + tid] = src[k * 64 + tid];
  __syncthreads();
  float run = 0.f;
  for (int c = 0; c < NCH; c++) {
    const float v = tile[c * HD + tid];
    tile[c * HD + tid] = run;
    run += v;
  }
  __syncthreads();
  float4* out = (float4*)p;
#pragma unroll 4
  for (int k = 0; k < (NCH * HD / 4) / 64; k++) out[k * 64 + tid] = dst[k * 64 + tid];
}

// ===== fused middle: tssa (pass 1) -> softmax over heads -> dots sums (pass 2)
// One block per (chunk, batch): 256 threads = 16 heads x 16 lanes.
// Pass 2 re-reads the same w lines (L2-hot) instead of a second HBM pass.
__global__ __launch_bounds__(256) void mid_fused(const bf16* __restrict__ w,
                                                 const float* __restrict__ S1ex,
                                                 const float* __restrict__ temp,
                                                 const float* __restrict__ gamma,
                                                 const float* __restrict__ penalty,
                                                 float* __restrict__ alpha_f,
                                                 float* __restrict__ S2,
                                                 float* __restrict__ SA) {
  const int c = blockIdx.x, b = blockIdx.y;
  const int tid = threadIdx.x, h = tid >> 4, l = tid & 15;
  __shared__ float sm_t[CHL][NHh + 1];   // tssa scores (padded rows: conflict-free col reads)
  __shared__ float sm_a[CHL][NHh + 1];   // alpha
  __shared__ float sm_g[NHh], sm_tv[NHh];
  if (tid < NHh) { sm_g[tid] = gamma[tid]; sm_tv[tid] = temp[tid]; }
  __syncthreads();

  const bf16* wp = w + ((size_t)(b * Tt + c * CHL)) * Dm + h * HD + l * 4;
  const float4 ex = *(const float4*)&S1ex[(((size_t)(b * NHh + h) * NCH) + c) * HD + l * 4];
  float a0 = ex.x, a1 = ex.y, a2 = ex.z, a3 = ex.w;
  const float tv = sm_tv[h];
#pragma unroll 8
  for (int i = 0; i < CHL; i++) {
    const ushort4 v = *(const ushort4*)(wp + (size_t)i * Dm);
    const float f0 = b2f(v.x), f1 = b2f(v.y), f2 = b2f(v.z), f3 = b2f(v.w);
    const float s0 = f0 * f0, s1 = f1 * f1, s2 = f2 * f2, s3 = f3 * f3;
    a0 += s0; a1 += s1; a2 += s2; a3 += s3;
    float val = s0 * frcp(fmaxf(a0, 1e-12f)) + s1 * frcp(fmaxf(a1, 1e-12f))
              + s2 * frcp(fmaxf(a2, 1e-12f)) + s3 * frcp(fmaxf(a3, 1e-12f));
    val += __shfl_xor(val, 1, 64);
    val += __shfl_xor(val, 2, 64);
    val += __shfl_xor(val, 4, 64);
    val += __shfl_xor(val, 8, 64);
    if (l == 0) sm_t[i][h] = tv * val;
  }
  __syncthreads();

  // softmax across heads: threads 0..31 each own one t
  if (tid < CHL) {
    const int t = tid;
    const float pen = penalty[(size_t)b * Tt + c * CHL + t];
    float sc[NHh];
    float mx = -1e30f;
#pragma unroll
    for (int hh = 0; hh < NHh; hh++) {
      sc[hh] = sm_t[t][hh] - sm_g[hh] * pen;
      mx = fmaxf(mx, sc[hh]);
    }
    float sum = 0.f;
#pragma unroll
    for (int hh = 0; hh < NHh; hh++) { const float e = __expf(sc[hh] - mx); sc[hh] = e; sum += e; }
    const float inv = 1.f / sum;
#pragma unroll
    for (int hh = 0; hh < NHh; hh++) sm_a[t][hh] = sc[hh] * inv;
  }
  __syncthreads();

  // write alpha [b,h,t] (16-lane contiguous per head)
#pragma unroll
  for (int k2 = 0; k2 < CHL / 16; k2++) {
    const int t = k2 * 16 + l;
    alpha_f[((size_t)(b * NHh + h)) * Tt + c * CHL + t] = sm_a[t][h];
  }

  // pass 2: dots chunk sums (w re-read is L2-hot)
  float d0 = 0.f, d1 = 0.f, d2 = 0.f, d3 = 0.f, sa = 0.f;
#pragma unroll 8
  for (int i = 0; i < CHL; i++) {
    const float a = sm_a[i][h];          // broadcast within 16-lane group
    const ushort4 v = *(const ushort4*)(wp + (size_t)i * Dm);
    const float f0 = b2f(v.x), f1 = b2f(v.y), f2 = b2f(v.z), f3 = b2f(v.w);
    d0 += f0 * f0 * a; d1 += f1 * f1 * a; d2 += f2 * f2 * a; d3 += f3 * f3 * a;
    sa += a;
  }
  float4 o; o.x = d0; o.y = d1; o.z = d2; o.w = d3;
  *(float4*)&S2[(((size_t)(b * NHh + h) * NCH) + c) * HD + l * 4] = o;
  if (l == 0) SA[(size_t)(b * NHh + h) * NCH + c] = sa;
}

// y'[b,t,h*64+d] = -w * alpha * min(1/(1+dots), 1e4), bf16 (vectorized 4 d/lane)
__global__ __launch_bounds__(64) void y_phase3(const bf16* __restrict__ w,
                                               const float* __restrict__ alpha_f,
                                               const float* __restrict__ S2ex,
                                               const float* __restrict__ SAex,
                                               bf16* __restrict__ yprime) {
  const int g = threadIdx.x >> 4, l = threadIdx.x & 15;
  const int c = blockIdx.x * 4 + g, h = blockIdx.y, b = blockIdx.z;
  const float4 ex = *(const float4*)&S2ex[(((size_t)(b * NHh + h) * NCH) + c) * HD + l * 4];
  float a0 = ex.x, a1 = ex.y, a2 = ex.z, a3 = ex.w;
  float acca = SAex[(size_t)(b * NHh + h) * NCH + c];
  const bf16* wp = w + ((size_t)(b * Tt + c * CHL)) * Dm + h * HD + l * 4;
  const float* ap = alpha_f + (size_t)(b * NHh + h) * Tt + c * CHL;
  bf16* yp = yprime + ((size_t)(b * Tt + c * CHL)) * Dm + h * HD + l * 4;
#pragma unroll 8
  for (int i = 0; i < CHL; i++) {
    const float a = ap[i];
    const ushort4 v = *(const ushort4*)(wp + (size_t)i * Dm);
    const float f0 = b2f(v.x), f1 = b2f(v.y), f2 = b2f(v.z), f3 = b2f(v.w);
    a0 += f0 * f0 * a; a1 += f1 * f1 * a; a2 += f2 * f2 * a; a3 += f3 * f3 * a;
    acca += a;
    const float rinv = frcp(acca + 1e-8f);
    const float at0 = fminf(frcp(1.f + a0 * rinv), 10000.f);
    const float at1 = fminf(frcp(1.f + a1 * rinv), 10000.f);
    const float at2 = fminf(frcp(1.f + a2 * rinv), 10000.f);
    const float at3 = fminf(frcp(1.f + a3 * rinv), 10000.f);
    ushort4 o;
    o.x = __bfloat16_as_ushort(__float2bfloat16(-f0 * a * at0));
    o.y = __bfloat16_as_ushort(__float2bfloat16(-f1 * a * at1));
    o.z = __bfloat16_as_ushort(__float2bfloat16(-f2 * a * at2));
    o.w = __bfloat16_as_ushort(__float2bfloat16(-f3 * a * at3));
    *(ushort4*)(yp + (size_t)i * Dm) = o;
  }
}

extern "C" void kernel_launch(void* const* d_in, const int* in_sizes, int n_in,
                              void* d_out, int out_size, void* d_ws, size_t ws_size,
                              hipStream_t stream) {
  const float* x     = (const float*)d_in[0];
  const float* phi   = (const float*)d_in[1];
  const float* Wattn = (const float*)d_in[2];
  const float* Wproj = (const float*)d_in[3];
  const float* gamma = (const float*)d_in[4];
  const float* temp  = (const float*)d_in[5];

  float* y_out    = (float*)d_out;                          // (B,T,D) fp32
  float* alpha_f  = y_out + (size_t)Bb * Tt * Dm;           // (B,NH,T) fp32

  char* ws = (char*)d_ws;
  bf16*  x_bf   = (bf16*)ws;  ws += (size_t)Bb * Tt * Dm * 2;         // 32 MB
  bf16*  Wa_bf  = (bf16*)ws;  ws += (size_t)Dm * Dm * 2;              // 2 MB
  bf16*  Wp_bf  = (bf16*)ws;  ws += (size_t)Dm * Dm * 2;              // 2 MB
  bf16*  w_bf   = (bf16*)ws;  ws += (size_t)Bb * Tt * Dm * 2;         // 32 MB
  float* pen    = (float*)ws; ws += (size_t)Bb * Tt * 4;              // 64 KB
  float* S1     = (float*)ws; ws += (size_t)Bb * NHh * NCH * HD * 4;  // 2 MB
  float* S2     = (float*)ws; ws += (size_t)Bb * NHh * NCH * HD * 4;  // 2 MB
  float* SA     = (float*)ws; ws += (size_t)Bb * NHh * NCH * 4;       // 32 KB
  bf16*  yprime = x_bf;  // alias: x_bf is dead after GEMM1

  static int attr_done = 0;
  if (!attr_done) {
    hipFuncSetAttribute((const void*)gemm256<true, true>,
                        hipFuncAttributeMaxDynamicSharedMemorySize, 131072);
    hipFuncSetAttribute((const void*)gemm256<false, false>,
                        hipFuncAttributeMaxDynamicSharedMemorySize, 131072);
    attr_done = 1;
  }

  const int M = Bb * Tt, N = Dm, K = Dm;
  dim3 gg((M / BM) * (N / BN)), gb(512);
  dim3 g3(NCH / 4, NHh, Bb), b64(64);

  cast_f32_to_bf16<<<dim3(1024), dim3(256), 0, stream>>>(x, x_bf, Bb * Tt * Dm);
  cast_f32_to_bf16<<<dim3(256), dim3(256), 0, stream>>>(Wattn, Wa_bf, Dm * Dm);
  cast_f32_to_bf16<<<dim3(256), dim3(256), 0, stream>>>(Wproj, Wp_bf, Dm * Dm);

  gemm256<true, true><<<gg, gb, 131072, stream>>>(x_bf, Wa_bf, (void*)w_bf, S1, M, N, K);
  phi_penalty_kernel<<<dim3(Bb), dim3(1024), 0, stream>>>(phi, pen);
  prefix_vec<<<dim3(Bb * NHh), b64, 0, stream>>>(S1);
  mid_fused<<<dim3(NCH, Bb), dim3(256), 0, stream>>>(w_bf, S1, temp, gamma, pen,
                                                     alpha_f, S2, SA);
  prefix_dots<<<dim3(Bb * NHh), b64, 0, stream>>>(S2, SA);
  y_phase3<<<g3, b64, 0, stream>>>(w_bf, alpha_f, S2, SA, yprime);
  gemm256<false, false><<<gg, gb, 131072, stream>>>(yprime, Wp_bf, (void*)y_out, nullptr, M, N, K);
}